// Round 1
// baseline (137.043 us; speedup 1.0000x reference)
//
#include <hip/hip_runtime.h>
#include <hip/hip_bf16.h>

// Problem constants (B,H,W,C = 32,32,32,256 -> l = 1024)
#define BATCH 32
#define L 1024
#define CD 256
#define BM 128         // pred rows per block
#define BN 128         // query cols per block
#define BK 64          // K per staging step (4 steps)
#define NRT (L / BM)   // 8 row tiles
#define NCT (L / BN)   // 8 col tiles

typedef __bf16 bf16x8 __attribute__((ext_vector_type(8)));
typedef __bf16 bf16x4 __attribute__((ext_vector_type(4)));
typedef float  f32x4  __attribute__((ext_vector_type(4)));

__device__ __forceinline__ unsigned int enc_f32(float f) {
    unsigned int u = __float_as_uint(f);
    return ((int)u < 0) ? ~u : (u | 0x80000000u);
}
__device__ __forceinline__ float dec_f32(unsigned int u) {
    u = (u & 0x80000000u) ? (u & 0x7FFFFFFFu) : ~u;
    return __uint_as_float(u);
}
__device__ __forceinline__ unsigned long long pmax(unsigned long long a, unsigned long long b) {
    return a > b ? a : b;
}
__device__ __forceinline__ bf16x4 cvt4(float4 v) {
    bf16x4 o;
    o[0] = (__bf16)v.x; o[1] = (__bf16)v.y; o[2] = (__bf16)v.z; o[3] = (__bf16)v.w;
    return o;
}

// Kernel 1: one block = one 128x128 output tile of M[b] = P[rows] . Q[cols]^T.
// 512 threads = 8 waves arranged 4 (row) x 2 (col); wave tile 32x64 (acc 2x4).
// K=256 staged in 4 steps of BK=64 through register-prefetched fp32->bf16
// conversion into XOR-swizzled LDS (conflict-free ds_write_b64 staging and
// ds_read_b128 fragment reads). Argmax epilogue runs ONCE per block:
// cheap f32 cmp scans in-thread, packed-u64 pmax only at combines.
__global__ __launch_bounds__(512, 4) void mm_argmax_kernel(
    const float* __restrict__ qg,   // feats1 [B][L][CD]  (queries)
    const float* __restrict__ pg,   // feats2 [B][L][CD]  (preds)
    unsigned long long* __restrict__ colpart,  // [B][NRT][L] (enc(val)<<32)|~a
    unsigned long long* __restrict__ rowpart)  // [B][NCT][L] (enc(val)<<32)|~j
{
    __shared__ __bf16 sA[BM * BK];            // 16384 B, swizzled
    __shared__ __bf16 sB[BN * BK];            // 16384 B, swizzled
    __shared__ unsigned long long sRow[2][BM]; // 2048 B
    __shared__ unsigned long long sCol[4][BN]; // 4096 B

    const int tid = threadIdx.x;
    const int bid = blockIdx.x;
    // bid = tile*32 + b: consecutive bids round-robin XCDs -> batch b sticks
    // to XCD b%8, so its P/Q panels stay L2/L3-local.
    const int b    = bid & 31;
    const int tile = bid >> 5;
    const int rt   = tile >> 3;
    const int ct   = tile & 7;
    const int row0 = rt * BM;
    const int col0 = ct * BN;

    const int lane = tid & 63;
    const int w    = tid >> 6;
    const int wm   = w >> 1;      // 0..3: wave rows wm*32
    const int wn   = w & 1;       // 0..1: wave cols wn*64
    const int quad = lane >> 4;
    const int l16  = lane & 15;

    const float* pA = pg + ((size_t)b * L + row0) * CD;  // preds rows
    const float* pB = qg + ((size_t)b * L + col0) * CD;  // query rows

    // staging decomposition: 16 threads/row (16B each, 256B contiguous/row),
    // 32 rows per pass, 4 passes -> 128 rows; 4 float4 per tile per thread.
    const int sr = tid >> 4;      // 0..31
    const int sl = tid & 15;      // float4 slot within 64-float row

    f32x4 acc[2][4];
    #pragma unroll
    for (int tm = 0; tm < 2; ++tm)
        #pragma unroll
        for (int tn = 0; tn < 4; ++tn) acc[tm][tn] = (f32x4){0.f, 0.f, 0.f, 0.f};

    // ---- prologue: prefetch k-step 0 ----
    float4 pfA[4], pfB[4];
    #pragma unroll
    for (int p = 0; p < 4; ++p) {
        pfA[p] = *(const float4*)(pA + (size_t)(p * 32 + sr) * CD + sl * 4);
        pfB[p] = *(const float4*)(pB + (size_t)(p * 32 + sr) * CD + sl * 4);
    }

    for (int step = 0; step < 4; ++step) {
        if (step) __syncthreads();   // B1: prev-step readers done
        // stage current step from prefetch regs (swizzle: 16B slot ^= row&7)
        #pragma unroll
        for (int p = 0; p < 4; ++p) {
            const int row = p * 32 + sr;
            const int idx = row * BK + (((sl >> 1) ^ (row & 7)) << 3) + ((sl & 1) << 2);
            *(bf16x4*)&sA[idx] = cvt4(pfA[p]);
            *(bf16x4*)&sB[idx] = cvt4(pfB[p]);
        }
        // issue prefetch for next step (overlaps barrier + MFMA phase)
        if (step < 3) {
            const int k0 = (step + 1) * BK;
            #pragma unroll
            for (int p = 0; p < 4; ++p) {
                pfA[p] = *(const float4*)(pA + (size_t)(p * 32 + sr) * CD + k0 + sl * 4);
                pfB[p] = *(const float4*)(pB + (size_t)(p * 32 + sr) * CD + k0 + sl * 4);
            }
        }
        __syncthreads();             // B2: sA/sB ready
        #pragma unroll
        for (int kk = 0; kk < 2; ++kk) {
            const int sw = ((kk * 4 + quad) ^ (l16 & 7)) << 3;  // bf16 units
            bf16x8 a0 = *(const bf16x8*)&sA[(wm * 32      + l16) * BK + sw];
            bf16x8 a1 = *(const bf16x8*)&sA[(wm * 32 + 16 + l16) * BK + sw];
            bf16x8 b0 = *(const bf16x8*)&sB[(wn * 64      + l16) * BK + sw];
            bf16x8 b1 = *(const bf16x8*)&sB[(wn * 64 + 16 + l16) * BK + sw];
            bf16x8 b2 = *(const bf16x8*)&sB[(wn * 64 + 32 + l16) * BK + sw];
            bf16x8 b3 = *(const bf16x8*)&sB[(wn * 64 + 48 + l16) * BK + sw];
            acc[0][0] = __builtin_amdgcn_mfma_f32_16x16x32_bf16(a0, b0, acc[0][0], 0, 0, 0);
            acc[0][1] = __builtin_amdgcn_mfma_f32_16x16x32_bf16(a0, b1, acc[0][1], 0, 0, 0);
            acc[0][2] = __builtin_amdgcn_mfma_f32_16x16x32_bf16(a0, b2, acc[0][2], 0, 0, 0);
            acc[0][3] = __builtin_amdgcn_mfma_f32_16x16x32_bf16(a0, b3, acc[0][3], 0, 0, 0);
            acc[1][0] = __builtin_amdgcn_mfma_f32_16x16x32_bf16(a1, b0, acc[1][0], 0, 0, 0);
            acc[1][1] = __builtin_amdgcn_mfma_f32_16x16x32_bf16(a1, b1, acc[1][1], 0, 0, 0);
            acc[1][2] = __builtin_amdgcn_mfma_f32_16x16x32_bf16(a1, b2, acc[1][2], 0, 0, 0);
            acc[1][3] = __builtin_amdgcn_mfma_f32_16x16x32_bf16(a1, b3, acc[1][3], 0, 0, 0);
        }
    }

    // ---- epilogue (once per block) ----
    // C/D layout (m89/m91): col = l16, row = quad*4 + r within each 16x16 frag.
    const int a_base = row0 + wm * 32 + quad * 4;  // + tm*16 + r
    const int j_base = col0 + wn * 64 + l16;       // + tn*16

    // column argmax over this block's 128 rows (ascending a => first-index ties)
    #pragma unroll
    for (int tn = 0; tn < 4; ++tn) {
        float cv = acc[0][tn][0];
        int   ca = a_base;
        #pragma unroll
        for (int tm = 0; tm < 2; ++tm)
            #pragma unroll
            for (int r = 0; r < 4; ++r) {
                if (tm == 0 && r == 0) continue;
                const float v = acc[tm][tn][r];
                const int   a = a_base + tm * 16 + r;
                if (v > cv) { cv = v; ca = a; }
            }
        unsigned long long pk =
            ((unsigned long long)enc_f32(cv) << 32) | (unsigned int)(~(unsigned int)ca);
        pk = pmax(pk, __shfl_xor(pk, 16));   // combine across quads (rows)
        pk = pmax(pk, __shfl_xor(pk, 32));
        if (quad == 0) sCol[wm][wn * 64 + tn * 16 + l16] = pk;
    }

    // row argmax over this block's 128 cols (ascending j => first-index ties)
    #pragma unroll
    for (int tm = 0; tm < 2; ++tm)
        #pragma unroll
        for (int r = 0; r < 4; ++r) {
            float rv = acc[tm][0][r];
            int   rj = j_base;
            #pragma unroll
            for (int tn = 1; tn < 4; ++tn) {
                const float v = acc[tm][tn][r];
                if (v > rv) { rv = v; rj = j_base + tn * 16; }
            }
            unsigned long long pk =
                ((unsigned long long)enc_f32(rv) << 32) | (unsigned int)(~(unsigned int)rj);
            pk = pmax(pk, __shfl_xor(pk, 1));  // combine across l16 (cols)
            pk = pmax(pk, __shfl_xor(pk, 2));
            pk = pmax(pk, __shfl_xor(pk, 4));
            pk = pmax(pk, __shfl_xor(pk, 8));
            if (l16 == 0) sRow[wn][wm * 32 + tm * 16 + quad * 4 + r] = pk;
        }

    __syncthreads();
    if (tid < BN) {
        unsigned long long c = pmax(pmax(sCol[0][tid], sCol[1][tid]),
                                    pmax(sCol[2][tid], sCol[3][tid]));
        colpart[((size_t)b * NRT + rt) * L + col0 + tid] = c;
        unsigned long long rr = pmax(sRow[0][tid], sRow[1][tid]);
        rowpart[((size_t)b * NCT + ct) * L + row0 + tid] = rr;
    }
}

// Kernel 2: parallel reduction of the 8-way partials.
// grid = 32 batches x 4 chunks; thread i handles one j (max1/val) and one a (max2).
__global__ __launch_bounds__(256) void reduce_kernel(
    const unsigned long long* __restrict__ colpart,  // [B][NRT][L]
    const unsigned long long* __restrict__ rowpart,  // [B][NCT][L]
    unsigned long long* __restrict__ bestc,          // [B][L] reduced col best
    int* __restrict__ max2)                          // [B][L]
{
    const int b   = blockIdx.x & 31;
    const int ch  = blockIdx.x >> 5;        // 0..3
    const int idx = ch * 256 + threadIdx.x; // 0..1023

    unsigned long long cb = 0ull;
    #pragma unroll
    for (int rt = 0; rt < NRT; ++rt)
        cb = pmax(cb, colpart[((size_t)b * NRT + rt) * L + idx]);
    bestc[(size_t)b * L + idx] = cb;

    unsigned long long rb = 0ull;
    #pragma unroll
    for (int ct = 0; ct < NCT; ++ct)
        rb = pmax(rb, rowpart[((size_t)b * NCT + ct) * L + idx]);
    max2[(size_t)b * L + idx] = (int)(~(unsigned int)rb) & (L - 1);
}

// Kernel 3: per-batch mutual-NN check + mean (tiny).
__global__ __launch_bounds__(256) void finalize_kernel(
    const unsigned long long* __restrict__ bestc,
    const int* __restrict__ max2,
    float* __restrict__ out)
{
    __shared__ int sMax2[L];
    __shared__ float sSum[4];
    __shared__ int sCnt[4];
    const int b = blockIdx.x;
    const int tid = threadIdx.x;

    for (int i = tid; i < L; i += 256) sMax2[i] = max2[(size_t)b * L + i];
    __syncthreads();

    float sum = 0.f;
    int cnt = 0;
    #pragma unroll
    for (int i = 0; i < 4; ++i) {
        const int j = tid + i * 256;
        const unsigned long long best = bestc[(size_t)b * L + j];
        const int a = (int)(~(unsigned int)best) & (L - 1);     // max1[j]
        const float val = dec_f32((unsigned int)(best >> 32));  // sims[j]
        if (sMax2[a] == j) { sum += val; ++cnt; }               // mutual NN
    }
    #pragma unroll
    for (int o = 32; o >= 1; o >>= 1) {
        sum += __shfl_down(sum, o);
        cnt += __shfl_down(cnt, o);
    }
    if ((tid & 63) == 0) { sSum[tid >> 6] = sum; sCnt[tid >> 6] = cnt; }
    __syncthreads();
    if (tid == 0) {
        float S = sSum[0] + sSum[1] + sSum[2] + sSum[3];
        int   C = sCnt[0] + sCnt[1] + sCnt[2] + sCnt[3];
        out[b] = S / fmaxf((float)C, 1.0f);
    }
}

extern "C" void kernel_launch(void* const* d_in, const int* in_sizes, int n_in,
                              void* d_out, int out_size, void* d_ws, size_t ws_size,
                              hipStream_t stream) {
    const float* q = (const float*)d_in[0];   // feats1 (queries)
    const float* p = (const float*)d_in[1];   // feats2 (preds)
    float* out = (float*)d_out;

    // ws layout: colpart [32][8][1024] u64 (2 MiB) | rowpart [32][8][1024] u64
    // (2 MiB) | bestc [32][1024] u64 (256 KiB) | max2 [32][1024] int (128 KiB).
    // Every slot written before read -> no init needed.
    unsigned long long* colpart = (unsigned long long*)d_ws;
    unsigned long long* rowpart = colpart + (size_t)BATCH * NRT * L;
    unsigned long long* bestc   = rowpart + (size_t)BATCH * NCT * L;
    int* max2 = (int*)(bestc + (size_t)BATCH * L);

    mm_argmax_kernel<<<BATCH * NRT * NCT, 512, 0, stream>>>(q, p, colpart, rowpart);
    reduce_kernel<<<BATCH * 4, 256, 0, stream>>>(colpart, rowpart, bestc, max2);
    finalize_kernel<<<BATCH, 256, 0, stream>>>(bestc, max2, out);
}

// Round 2
// 129.428 us; speedup vs baseline: 1.0588x; 1.0588x over previous
//
#include <hip/hip_runtime.h>
#include <hip/hip_bf16.h>

// Problem constants (B,H,W,C = 32,32,32,256 -> l = 1024)
#define BATCH 32
#define L 1024
#define CD 256
#define BM 128         // pred rows per block
#define BN 128         // query cols per block
#define BK 64          // K per staging step (4 steps)
#define NRT (L / BM)   // 8 row tiles
#define NCT (L / BN)   // 8 col tiles

typedef __bf16 bf16x8 __attribute__((ext_vector_type(8)));
typedef __bf16 bf16x4 __attribute__((ext_vector_type(4)));
typedef float  f32x4  __attribute__((ext_vector_type(4)));

__device__ __forceinline__ unsigned int enc_f32(float f) {
    unsigned int u = __float_as_uint(f);
    return ((int)u < 0) ? ~u : (u | 0x80000000u);
}
__device__ __forceinline__ float dec_f32(unsigned int u) {
    u = (u & 0x80000000u) ? (u & 0x7FFFFFFFu) : ~u;
    return __uint_as_float(u);
}
__device__ __forceinline__ unsigned long long pmax(unsigned long long a, unsigned long long b) {
    return a > b ? a : b;
}
__device__ __forceinline__ bf16x4 cvt4(float4 v) {
    bf16x4 o;
    o[0] = (__bf16)v.x; o[1] = (__bf16)v.y; o[2] = (__bf16)v.z; o[3] = (__bf16)v.w;
    return o;
}

// lgkm-only barrier: does NOT drain vmcnt, so prefetch global loads stay in
// flight across the barrier (the whole point — __syncthreads() waits vmcnt(0)).
// asm "memory" clobbers fence the compiler on both sides so ds ops can't cross.
__device__ __forceinline__ void block_sync_lgkm() {
    asm volatile("s_waitcnt lgkmcnt(0)" ::: "memory");
    __builtin_amdgcn_s_barrier();
    asm volatile("" ::: "memory");
}

// Kernel 1: one block = one 128x128 output tile of M[b] = P[rows] . Q[cols]^T.
// 512 threads = 8 waves arranged 4 (row) x 2 (col); wave tile 32x64 (acc 2x4).
// K=256 in 4 steps of BK=64, DOUBLE-buffered LDS, one lgkm-only barrier per
// step. Steady state: compute buf[cur] while next step's global loads fly;
// stage into buf[cur^1] (nobody reads it); issue step+2 loads; barrier.
__global__ __launch_bounds__(512, 4) void mm_argmax_kernel(
    const float* __restrict__ qg,   // feats1 [B][L][CD]  (queries)
    const float* __restrict__ pg,   // feats2 [B][L][CD]  (preds)
    unsigned long long* __restrict__ colpart,  // [B][NRT][L] (enc(val)<<32)|~a
    unsigned long long* __restrict__ rowpart)  // [B][NCT][L] (enc(val)<<32)|~j
{
    __shared__ __bf16 sA[2][BM * BK];          // 2 x 16384 B, swizzled
    __shared__ __bf16 sB[2][BN * BK];          // 2 x 16384 B, swizzled
    __shared__ unsigned long long sRow[2][BM]; // 2048 B
    __shared__ unsigned long long sCol[4][BN]; // 4096 B

    const int tid = threadIdx.x;
    const int bid = blockIdx.x;
    // bid = tile*32 + b: consecutive bids round-robin XCDs -> batch b sticks
    // to XCD b%8, so its P/Q panels stay L2/L3-local.
    const int b    = bid & 31;
    const int tile = bid >> 5;
    const int rt   = tile >> 3;
    const int ct   = tile & 7;
    const int row0 = rt * BM;
    const int col0 = ct * BN;

    const int lane = tid & 63;
    const int w    = tid >> 6;
    const int wm   = w >> 1;      // 0..3: wave rows wm*32
    const int wn   = w & 1;       // 0..1: wave cols wn*64
    const int quad = lane >> 4;
    const int l16  = lane & 15;

    const float* pA = pg + ((size_t)b * L + row0) * CD;  // preds rows
    const float* pB = qg + ((size_t)b * L + col0) * CD;  // query rows

    // staging decomposition: 16 threads/row (16B each, 256B contiguous/row),
    // 32 rows per pass, 4 passes -> 128 rows; 4 float4 per array per thread.
    const int sr = tid >> 4;      // 0..31
    const int sl = tid & 15;      // float4 slot within 64-float row

    f32x4 acc[2][4];
    #pragma unroll
    for (int tm = 0; tm < 2; ++tm)
        #pragma unroll
        for (int tn = 0; tn < 4; ++tn) acc[tm][tn] = (f32x4){0.f, 0.f, 0.f, 0.f};

    float4 pfA[4], pfB[4];

    #define LOADS(k0)                                                          \
        _Pragma("unroll")                                                      \
        for (int p = 0; p < 4; ++p) {                                          \
            pfA[p] = *(const float4*)(pA + (size_t)(p * 32 + sr) * CD + (k0) + sl * 4); \
            pfB[p] = *(const float4*)(pB + (size_t)(p * 32 + sr) * CD + (k0) + sl * 4); \
        }

    // swizzle: 16B slot index ^= row&7 (conflict-free writes and b128 reads)
    #define STAGE(buf)                                                         \
        _Pragma("unroll")                                                      \
        for (int p = 0; p < 4; ++p) {                                          \
            const int row_ = p * 32 + sr;                                      \
            const int idx_ = row_ * BK + (((sl >> 1) ^ (row_ & 7)) << 3) + ((sl & 1) << 2); \
            *(bf16x4*)&sA[buf][idx_] = cvt4(pfA[p]);                           \
            *(bf16x4*)&sB[buf][idx_] = cvt4(pfB[p]);                           \
        }

    #define COMPUTE(buf)                                                       \
        __builtin_amdgcn_s_setprio(1);                                         \
        _Pragma("unroll")                                                      \
        for (int kk = 0; kk < 2; ++kk) {                                       \
            const int sw = ((kk * 4 + quad) ^ (l16 & 7)) << 3;                 \
            bf16x8 a0 = *(const bf16x8*)&sA[buf][(wm * 32      + l16) * BK + sw]; \
            bf16x8 a1 = *(const bf16x8*)&sA[buf][(wm * 32 + 16 + l16) * BK + sw]; \
            bf16x8 b0 = *(const bf16x8*)&sB[buf][(wn * 64      + l16) * BK + sw]; \
            bf16x8 b1 = *(const bf16x8*)&sB[buf][(wn * 64 + 16 + l16) * BK + sw]; \
            bf16x8 b2 = *(const bf16x8*)&sB[buf][(wn * 64 + 32 + l16) * BK + sw]; \
            bf16x8 b3 = *(const bf16x8*)&sB[buf][(wn * 64 + 48 + l16) * BK + sw]; \
            acc[0][0] = __builtin_amdgcn_mfma_f32_16x16x32_bf16(a0, b0, acc[0][0], 0, 0, 0); \
            acc[0][1] = __builtin_amdgcn_mfma_f32_16x16x32_bf16(a0, b1, acc[0][1], 0, 0, 0); \
            acc[0][2] = __builtin_amdgcn_mfma_f32_16x16x32_bf16(a0, b2, acc[0][2], 0, 0, 0); \
            acc[0][3] = __builtin_amdgcn_mfma_f32_16x16x32_bf16(a0, b3, acc[0][3], 0, 0, 0); \
            acc[1][0] = __builtin_amdgcn_mfma_f32_16x16x32_bf16(a1, b0, acc[1][0], 0, 0, 0); \
            acc[1][1] = __builtin_amdgcn_mfma_f32_16x16x32_bf16(a1, b1, acc[1][1], 0, 0, 0); \
            acc[1][2] = __builtin_amdgcn_mfma_f32_16x16x32_bf16(a1, b2, acc[1][2], 0, 0, 0); \
            acc[1][3] = __builtin_amdgcn_mfma_f32_16x16x32_bf16(a1, b3, acc[1][3], 0, 0, 0); \
        }                                                                      \
        __builtin_amdgcn_s_setprio(0);

    // ---- prologue ----
    LOADS(0);
    STAGE(0);            // compiler inserts counted vmcnt before first cvt use
    LOADS(BK);           // step-1 loads fly across the barrier + compute(0)
    block_sync_lgkm();

    // ---- pipelined K-loop: one lgkm-only barrier per step ----
    COMPUTE(0);
    STAGE(1);            // waits (counted) on step-1 loads only
    LOADS(2 * BK);       // step-2 loads in flight across barrier + compute(1)
    block_sync_lgkm();

    COMPUTE(1);
    STAGE(0);
    LOADS(3 * BK);
    block_sync_lgkm();

    COMPUTE(0);
    STAGE(1);
    block_sync_lgkm();

    COMPUTE(1);

    #undef LOADS
    #undef STAGE
    #undef COMPUTE

    // ---- epilogue (once per block) ----
    // C/D layout (m89/m91): col = l16, row = quad*4 + r within each 16x16 frag.
    const int a_base = row0 + wm * 32 + quad * 4;  // + tm*16 + r
    const int j_base = col0 + wn * 64 + l16;       // + tn*16

    // column argmax over this block's 128 rows (ascending a => first-index ties)
    #pragma unroll
    for (int tn = 0; tn < 4; ++tn) {
        float cv = acc[0][tn][0];
        int   ca = a_base;
        #pragma unroll
        for (int tm = 0; tm < 2; ++tm)
            #pragma unroll
            for (int r = 0; r < 4; ++r) {
                if (tm == 0 && r == 0) continue;
                const float v = acc[tm][tn][r];
                const int   a = a_base + tm * 16 + r;
                if (v > cv) { cv = v; ca = a; }
            }
        unsigned long long pk =
            ((unsigned long long)enc_f32(cv) << 32) | (unsigned int)(~(unsigned int)ca);
        pk = pmax(pk, __shfl_xor(pk, 16));   // combine across quads (rows)
        pk = pmax(pk, __shfl_xor(pk, 32));
        if (quad == 0) sCol[wm][wn * 64 + tn * 16 + l16] = pk;
    }

    // row argmax over this block's 128 cols (ascending j => first-index ties)
    #pragma unroll
    for (int tm = 0; tm < 2; ++tm)
        #pragma unroll
        for (int r = 0; r < 4; ++r) {
            float rv = acc[tm][0][r];
            int   rj = j_base;
            #pragma unroll
            for (int tn = 1; tn < 4; ++tn) {
                const float v = acc[tm][tn][r];
                if (v > rv) { rv = v; rj = j_base + tn * 16; }
            }
            unsigned long long pk =
                ((unsigned long long)enc_f32(rv) << 32) | (unsigned int)(~(unsigned int)rj);
            pk = pmax(pk, __shfl_xor(pk, 1));  // combine across l16 (cols)
            pk = pmax(pk, __shfl_xor(pk, 2));
            pk = pmax(pk, __shfl_xor(pk, 4));
            pk = pmax(pk, __shfl_xor(pk, 8));
            if (l16 == 0) sRow[wn][wm * 32 + tm * 16 + quad * 4 + r] = pk;
        }

    __syncthreads();
    if (tid < BN) {
        unsigned long long c = pmax(pmax(sCol[0][tid], sCol[1][tid]),
                                    pmax(sCol[2][tid], sCol[3][tid]));
        colpart[((size_t)b * NRT + rt) * L + col0 + tid] = c;
        unsigned long long rr = pmax(sRow[0][tid], sRow[1][tid]);
        rowpart[((size_t)b * NCT + ct) * L + row0 + tid] = rr;
    }
}

// Kernel 2: merged reduce + mutual-NN + mean. One block per batch, 1024 thr:
// thread j reduces rowpart over ct (-> sMax2) and colpart over rt (-> reg),
// then the mutual check. Saves a launch + the bestc/max2 global round-trip.
__global__ __launch_bounds__(1024) void finalize_kernel(
    const unsigned long long* __restrict__ colpart,  // [B][NRT][L]
    const unsigned long long* __restrict__ rowpart,  // [B][NCT][L]
    float* __restrict__ out)
{
    __shared__ int sMax2[L];
    __shared__ float sSum[16];
    __shared__ int sCnt[16];
    const int b = blockIdx.x;
    const int j = threadIdx.x;        // 0..1023

    unsigned long long rb = 0ull;
    #pragma unroll
    for (int ct = 0; ct < NCT; ++ct)
        rb = pmax(rb, rowpart[((size_t)b * NCT + ct) * L + j]);
    sMax2[j] = (int)(~(unsigned int)rb) & (L - 1);

    unsigned long long cb = 0ull;
    #pragma unroll
    for (int rt = 0; rt < NRT; ++rt)
        cb = pmax(cb, colpart[((size_t)b * NRT + rt) * L + j]);
    __syncthreads();

    const int a = (int)(~(unsigned int)cb) & (L - 1);      // max1[j]
    const float val = dec_f32((unsigned int)(cb >> 32));   // sims[j]
    const bool mut = (sMax2[a] == j);                      // mutual NN
    float sum = mut ? val : 0.f;
    int   cnt = mut ? 1 : 0;

    #pragma unroll
    for (int o = 32; o >= 1; o >>= 1) {
        sum += __shfl_down(sum, o);
        cnt += __shfl_down(cnt, o);
    }
    if ((j & 63) == 0) { sSum[j >> 6] = sum; sCnt[j >> 6] = cnt; }
    __syncthreads();
    if (j == 0) {
        float S = 0.f;
        int   C = 0;
        #pragma unroll
        for (int i = 0; i < 16; ++i) { S += sSum[i]; C += sCnt[i]; }
        out[b] = S / fmaxf((float)C, 1.0f);
    }
}

extern "C" void kernel_launch(void* const* d_in, const int* in_sizes, int n_in,
                              void* d_out, int out_size, void* d_ws, size_t ws_size,
                              hipStream_t stream) {
    const float* q = (const float*)d_in[0];   // feats1 (queries)
    const float* p = (const float*)d_in[1];   // feats2 (preds)
    float* out = (float*)d_out;

    // ws layout: colpart [32][8][1024] u64 (2 MiB) | rowpart [32][8][1024] u64
    // (2 MiB). Every slot written before read -> no init needed.
    unsigned long long* colpart = (unsigned long long*)d_ws;
    unsigned long long* rowpart = colpart + (size_t)BATCH * NRT * L;

    mm_argmax_kernel<<<BATCH * NRT * NCT, 512, 0, stream>>>(q, p, colpart, rowpart);
    finalize_kernel<<<BATCH, 1024, 0, stream>>>(colpart, rowpart, out);
}